// Round 1
// baseline (357.230 us; speedup 1.0000x reference)
//
#include <hip/hip_runtime.h>

#define NPTS 8192
#define BATCH 4
#define SEGS 8
#define SEGLEN (NPTS / SEGS)

// ---------------------------------------------------------------------------
// init: set per-point min arrays (2 * B * N floats, stored as uint bits) to
// +inf, and zero the scalar output (harness poisons d_out/d_ws with 0xAA).
// ---------------------------------------------------------------------------
__global__ void init_kernel(unsigned* __restrict__ mins, float* __restrict__ out) {
    int i = blockIdx.x * blockDim.x + threadIdx.x;
    if (i < 2 * BATCH * NPTS) mins[i] = 0x7F800000u;  // +inf
    if (i == 0) out[0] = 0.0f;
}

// ---------------------------------------------------------------------------
// chamfer: dir 0 = for each x point, min over y; dir 1 = for each y point,
// min over x. Each thread owns one query point; the inner loop walks a
// 1024-point segment of the other set with block-uniform addresses so the
// compiler emits scalar s_load for the segment data (no VALU/LDS cost).
// Partial mins are merged via atomicMin on float bits (all distances >= 0).
// ---------------------------------------------------------------------------
__global__ __launch_bounds__(256) void chamfer_kernel(
    const float* __restrict__ x, const float* __restrict__ y,
    unsigned* __restrict__ mins) {
    const int dir = blockIdx.z;
    const int b = blockIdx.y;
    const int pointBlock = blockIdx.x / SEGS;
    const int seg = blockIdx.x % SEGS;

    const float* pts = dir ? y : x;   // query set
    const float* oth = dir ? x : y;   // target set
    unsigned* outmin = mins + dir * (BATCH * NPTS);

    const int pi = pointBlock * 256 + (int)threadIdx.x;   // 0..8191
    const float* p = pts + (size_t)(b * NPTS + pi) * 3;
    const float px = p[0], py = p[1], pz = p[2];

    // block-uniform segment base -> scalar loads inside the loop
    const float* q = oth + (size_t)(b * NPTS + seg * SEGLEN) * 3;

    float best = 3.0e38f;
#pragma unroll 8
    for (int j = 0; j < SEGLEN; ++j) {
        const float qx = q[3 * j + 0];
        const float qy = q[3 * j + 1];
        const float qz = q[3 * j + 2];
        const float dx = px - qx;
        const float dy = py - qy;
        const float dz = pz - qz;
        const float d = fmaf(dz, dz, fmaf(dy, dy, dx * dx));
        best = fminf(best, d);
    }
    atomicMin(&outmin[b * NPTS + pi], __float_as_uint(best));
}

// ---------------------------------------------------------------------------
// regularizer: tiny (B=4, 3x3). One thread. Faithful to the reference:
//   R_loss = R_gt^T @ R - I per batch, sum of squares
//   S_diag = jnp.diagonal(S, axis1=0, axis2=1) -> S_diag[a,d] = S[d,d,a]
//   t squeezed (B,3) vs t_gt (B,3)
// ---------------------------------------------------------------------------
__global__ void reg_kernel(const float* __restrict__ R, const float* __restrict__ S,
                           const float* __restrict__ t, const float* __restrict__ R_gt,
                           const float* __restrict__ S_gt, const float* __restrict__ t_gt,
                           float* __restrict__ out) {
    if (threadIdx.x == 0 && blockIdx.x == 0) {
        float acc = 0.0f;
        for (int b = 0; b < BATCH; ++b)
            for (int i = 0; i < 3; ++i)
                for (int k = 0; k < 3; ++k) {
                    float s = 0.0f;
                    for (int j = 0; j < 3; ++j)
                        s += R_gt[b * 9 + j * 3 + i] * R[b * 9 + j * 3 + k];
                    s -= (i == k) ? 1.0f : 0.0f;
                    acc += s * s;
                }
        // diagonal over (batch,row): only d in 0..2
        for (int d = 0; d < 3; ++d)
            for (int a = 0; a < 3; ++a) {
                const float diff = S[d * 9 + d * 3 + a] - S_gt[d * 9 + d * 3 + a];
                acc += diff * diff;
            }
        for (int b = 0; b < BATCH; ++b)
            for (int k = 0; k < 3; ++k) {
                const float diff = t[b * 3 + k] - t_gt[b * 3 + k];
                acc += diff * diff;
            }
        atomicAdd(out, acc);
    }
}

// ---------------------------------------------------------------------------
// finalize: sum all 2*B*N mins, scaled by 1/(B*N) (mean over points then
// mean over batch; B*N == B*M == 32768), atomicAdd into the scalar output.
// ---------------------------------------------------------------------------
__global__ __launch_bounds__(512) void finalize_kernel(const unsigned* __restrict__ mins,
                                                       float* __restrict__ out) {
    const int i = blockIdx.x * blockDim.x + threadIdx.x;
    float v = __uint_as_float(mins[i]) * (1.0f / (BATCH * NPTS));
    // wave64 reduce
    for (int off = 32; off; off >>= 1) v += __shfl_down(v, off, 64);
    __shared__ float wsum[8];
    const int lane = threadIdx.x & 63;
    const int wave = threadIdx.x >> 6;
    if (lane == 0) wsum[wave] = v;
    __syncthreads();
    if (wave == 0) {
        v = (lane < 8) ? wsum[lane] : 0.0f;
        for (int off = 4; off; off >>= 1) v += __shfl_down(v, off, 64);
        if (lane == 0) atomicAdd(out, v);
    }
}

extern "C" void kernel_launch(void* const* d_in, const int* in_sizes, int n_in,
                              void* d_out, int out_size, void* d_ws, size_t ws_size,
                              hipStream_t stream) {
    const float* x    = (const float*)d_in[0];  // [4, 8192, 3]
    const float* y    = (const float*)d_in[1];  // [4, 8192, 3]
    const float* R    = (const float*)d_in[2];  // [4, 3, 3]
    const float* S    = (const float*)d_in[3];  // [4, 3, 3]
    const float* t    = (const float*)d_in[4];  // [4, 3, 1]
    const float* R_gt = (const float*)d_in[5];  // [4, 3, 3]
    const float* S_gt = (const float*)d_in[6];  // [4, 3, 3]
    const float* t_gt = (const float*)d_in[7];  // [4, 3]
    float* out = (float*)d_out;
    unsigned* mins = (unsigned*)d_ws;  // 2 * BATCH * NPTS uints = 256 KiB

    // init mins to +inf, out to 0
    init_kernel<<<dim3((2 * BATCH * NPTS + 255) / 256), dim3(256), 0, stream>>>(mins, out);

    // chamfer both directions: grid (pointBlocks*SEGS, B, 2)
    chamfer_kernel<<<dim3((NPTS / 256) * SEGS, BATCH, 2), dim3(256), 0, stream>>>(x, y, mins);

    // tiny regularizer
    reg_kernel<<<dim3(1), dim3(64), 0, stream>>>(R, S, t, R_gt, S_gt, t_gt, out);

    // reduce mins into the scalar
    finalize_kernel<<<dim3((2 * BATCH * NPTS) / 512), dim3(512), 0, stream>>>(mins, out);
}

// Round 2
// 138.202 us; speedup vs baseline: 2.5848x; 2.5848x over previous
//
#include <hip/hip_runtime.h>

#define NPTS 8192
#define BATCH 4
#define NQ 4              // queries per thread (register-blocked)
#define BLOCK 256
#define QPB (BLOCK * NQ)  // 1024 queries per block
#define QBLOCKS (NPTS / QPB)  // 8

// ---------------------------------------------------------------------------
// chamfer: grid (QBLOCKS * SEGS, BATCH, 2). Each block: 1024 query points
// (4 per thread, register-resident) x one SEGLEN-point target segment staged
// in LDS as float4. Inner loop: 1 ds_read_b128 broadcast + 28 VALU ops.
// Partial mins stored (no atomics) to ws[(dir*BATCH+b)*SEGS+seg][query].
// ---------------------------------------------------------------------------
__global__ __launch_bounds__(256) void chamfer_kernel(
    const float* __restrict__ x, const float* __restrict__ y,
    float* __restrict__ ws, int segShift, int segLen) {
    __shared__ float4 tgt[1024];  // up to 1024 points (16 KB)

    const int dir = blockIdx.z;
    const int b = blockIdx.y;
    const int seg = blockIdx.x & ((1 << segShift) - 1);
    const int qb = blockIdx.x >> segShift;
    const int segs = 1 << segShift;

    const float* pts = dir ? y : x;   // query set
    const float* oth = dir ? x : y;   // target set

    // stage target segment into LDS (one-time, coalesced-ish)
    const float* q0 = oth + ((size_t)b * NPTS + (size_t)seg * segLen) * 3;
    for (int p = threadIdx.x; p < segLen; p += BLOCK) {
        tgt[p] = make_float4(q0[3 * p], q0[3 * p + 1], q0[3 * p + 2], 0.0f);
    }

    // query points -> registers
    float px[NQ], py[NQ], pz[NQ], best[NQ];
    const int qbase = b * NPTS + qb * QPB + (int)threadIdx.x;
#pragma unroll
    for (int k = 0; k < NQ; ++k) {
        const float* p = pts + (size_t)(qbase + k * BLOCK) * 3;
        px[k] = p[0];
        py[k] = p[1];
        pz[k] = p[2];
        best[k] = 3.0e38f;
    }

    __syncthreads();

#pragma unroll 4
    for (int j = 0; j < segLen; ++j) {
        const float4 t4 = tgt[j];
#pragma unroll
        for (int k = 0; k < NQ; ++k) {
            const float dx = px[k] - t4.x;
            const float dy = py[k] - t4.y;
            const float dz = pz[k] - t4.z;
            const float d = fmaf(dz, dz, fmaf(dy, dy, dx * dx));
            best[k] = fminf(best[k], d);
        }
    }

    float* wrow = ws + ((size_t)((dir * BATCH + b) * segs + seg)) * NPTS +
                  qb * QPB + threadIdx.x;
#pragma unroll
    for (int k = 0; k < NQ; ++k) wrow[k * BLOCK] = best[k];
}

// ---------------------------------------------------------------------------
// finalize: min over segments per query, mean-scale, block-reduce, one
// atomicAdd per block. Thread (0,0) also adds the tiny regularizer term:
//   sum((R_gt^T R - I)^2) + sum((diag_{b,r}(S) - diag(S_gt))^2) + sum((t-t_gt)^2)
// ---------------------------------------------------------------------------
__global__ __launch_bounds__(256) void finalize_kernel(
    const float* __restrict__ ws, const float* __restrict__ R,
    const float* __restrict__ S, const float* __restrict__ t,
    const float* __restrict__ R_gt, const float* __restrict__ S_gt,
    const float* __restrict__ t_gt, float* __restrict__ out, int segs) {
    const int gid = blockIdx.x * BLOCK + (int)threadIdx.x;  // 0 .. 2*B*N-1
    const int db = gid >> 13;      // (dir*BATCH + b)
    const int q = gid & (NPTS - 1);

    const float* p = ws + (size_t)db * segs * NPTS + q;
    float m = p[0];
    for (int s = 1; s < segs; ++s) m = fminf(m, p[(size_t)s * NPTS]);
    float v = m * (1.0f / (BATCH * NPTS));

    if (gid == 0) {
        float acc = 0.0f;
        for (int b = 0; b < BATCH; ++b)
            for (int i = 0; i < 3; ++i)
                for (int k = 0; k < 3; ++k) {
                    float s = 0.0f;
                    for (int j = 0; j < 3; ++j)
                        s += R_gt[b * 9 + j * 3 + i] * R[b * 9 + j * 3 + k];
                    s -= (i == k) ? 1.0f : 0.0f;
                    acc += s * s;
                }
        for (int d = 0; d < 3; ++d)  // jnp.diagonal(S, axis1=0, axis2=1)
            for (int a = 0; a < 3; ++a) {
                const float diff = S[d * 9 + d * 3 + a] - S_gt[d * 9 + d * 3 + a];
                acc += diff * diff;
            }
        for (int b = 0; b < BATCH; ++b)
            for (int k = 0; k < 3; ++k) {
                const float diff = t[b * 3 + k] - t_gt[b * 3 + k];
                acc += diff * diff;
            }
        v += acc;
    }

    // block reduction (4 waves of 64)
    for (int off = 32; off; off >>= 1) v += __shfl_down(v, off, 64);
    __shared__ float wsum[4];
    const int lane = threadIdx.x & 63;
    const int wave = threadIdx.x >> 6;
    if (lane == 0) wsum[wave] = v;
    __syncthreads();
    if (wave == 0) {
        v = (lane < 4) ? wsum[lane] : 0.0f;
        for (int off = 2; off; off >>= 1) v += __shfl_down(v, off, 64);
        if (lane == 0) atomicAdd(out, v);
    }
}

extern "C" void kernel_launch(void* const* d_in, const int* in_sizes, int n_in,
                              void* d_out, int out_size, void* d_ws, size_t ws_size,
                              hipStream_t stream) {
    const float* x    = (const float*)d_in[0];
    const float* y    = (const float*)d_in[1];
    const float* R    = (const float*)d_in[2];
    const float* S    = (const float*)d_in[3];
    const float* t    = (const float*)d_in[4];
    const float* R_gt = (const float*)d_in[5];
    const float* S_gt = (const float*)d_in[6];
    const float* t_gt = (const float*)d_in[7];
    float* out = (float*)d_out;
    float* ws = (float*)d_ws;

    // pick segment count by available scratch: need 2*B*SEGS*N floats
    int segShift = 4;  // SEGS=16 -> 4 MB scratch, SEGLEN=512
    if (ws_size < (size_t)2 * BATCH * 16 * NPTS * sizeof(float)) segShift = 3;  // 2 MB
    const int segs = 1 << segShift;
    const int segLen = NPTS / segs;

    hipMemsetAsync(out, 0, sizeof(float), stream);

    chamfer_kernel<<<dim3(QBLOCKS * segs, BATCH, 2), dim3(BLOCK), 0, stream>>>(
        x, y, ws, segShift, segLen);

    finalize_kernel<<<dim3(2 * BATCH * NPTS / BLOCK), dim3(BLOCK), 0, stream>>>(
        ws, R, S, t, R_gt, S_gt, t_gt, out, segs);
}

// Round 3
// 125.318 us; speedup vs baseline: 2.8506x; 1.1028x over previous
//
#include <hip/hip_runtime.h>

#define NPTS 8192
#define BATCH 4
#define BLOCK 256
#define NQ 4                   // queries per thread
#define QPB (BLOCK * NQ)       // 1024 queries per block
#define QBLOCKS (NPTS / QPB)   // 8
#define SEGS 32
#define SEGLEN (NPTS / SEGS)   // 256 targets per segment

// ---------------------------------------------------------------------------
// chamfer: grid (QBLOCKS*SEGS, BATCH, 2). Expanded-form distances:
//   d = |p|^2 + |q|^2 - 2 p.q
// LDS holds the segment as paired float4s:
//   tgtA[j] = {x0, x1, y0, y1}, tgtB[j] = {z0, z1, |q0|^2, |q1|^2}
// Inner cost per 2 targets per query: 6 v_fma + 1 v_min3.
// Partial mins merged via atomicMin on float bits (values clamped >= 0).
// ---------------------------------------------------------------------------
__global__ __launch_bounds__(256) void chamfer_kernel(
    const float* __restrict__ x, const float* __restrict__ y,
    unsigned* __restrict__ mins) {
    __shared__ float4 tgtA[SEGLEN / 2];
    __shared__ float4 tgtB[SEGLEN / 2];

    const int dir = blockIdx.z;
    const int b = blockIdx.y;
    const int seg = blockIdx.x & (SEGS - 1);
    const int qb = blockIdx.x >> 5;  // / SEGS

    const float* pts = dir ? y : x;  // query set
    const float* oth = dir ? x : y;  // target set

    // stage one segment: one point per thread (SEGLEN == BLOCK)
    {
        const int p = threadIdx.x;
        const float* q = oth + ((size_t)b * NPTS + seg * SEGLEN + p) * 3;
        const float qx = q[0], qy = q[1], qz = q[2];
        const float sq = fmaf(qz, qz, fmaf(qy, qy, qx * qx));
        float* A = (float*)tgtA;
        float* Bv = (float*)tgtB;
        const int pi = p >> 1, par = p & 1;
        A[pi * 4 + par] = qx;
        A[pi * 4 + 2 + par] = qy;
        Bv[pi * 4 + par] = qz;
        Bv[pi * 4 + 2 + par] = sq;
    }

    // query points -> registers (-2*p components, |p|^2 folded in at the end)
    float m2x[NQ], m2y[NQ], m2z[NQ], sp[NQ], best[NQ];
    const int qbase = b * NPTS + qb * QPB + (int)threadIdx.x;
#pragma unroll
    for (int k = 0; k < NQ; ++k) {
        const float* p = pts + (size_t)(qbase + k * BLOCK) * 3;
        const float px = p[0], py = p[1], pz = p[2];
        m2x[k] = -2.0f * px;
        m2y[k] = -2.0f * py;
        m2z[k] = -2.0f * pz;
        sp[k] = fmaf(pz, pz, fmaf(py, py, px * px));
        best[k] = 3.0e38f;
    }

    __syncthreads();

#pragma unroll 2
    for (int j = 0; j < SEGLEN / 2; ++j) {
        const float4 A = tgtA[j];
        const float4 Bv = tgtB[j];
#pragma unroll
        for (int k = 0; k < NQ; ++k) {
            float d0 = fmaf(m2x[k], A.x, Bv.z);   // x0, sq0
            d0 = fmaf(m2y[k], A.z, d0);           // y0
            d0 = fmaf(m2z[k], Bv.x, d0);          // z0
            float d1 = fmaf(m2x[k], A.y, Bv.w);   // x1, sq1
            d1 = fmaf(m2y[k], A.w, d1);           // y1
            d1 = fmaf(m2z[k], Bv.y, d1);          // z1
            best[k] = fminf(fminf(best[k], d0), d1);  // v_min3_f32
        }
    }

    unsigned* om = mins + (size_t)(dir * BATCH + b) * NPTS + qb * QPB + threadIdx.x;
#pragma unroll
    for (int k = 0; k < NQ; ++k) {
        const float d = fmaxf(sp[k] + best[k], 0.0f);  // >=0 so uint order == float order
        atomicMin(&om[k * BLOCK], __float_as_uint(d));
    }
}

// ---------------------------------------------------------------------------
// finalize: ONE block, 1024 threads. Sum all 2*B*N mins (256 KB), scale by
// 1/(B*N), add the tiny regularizer (thread 0), write out[0] directly.
// ---------------------------------------------------------------------------
__global__ __launch_bounds__(1024) void finalize_kernel(
    const unsigned* __restrict__ mins, const float* __restrict__ R,
    const float* __restrict__ S, const float* __restrict__ t,
    const float* __restrict__ R_gt, const float* __restrict__ S_gt,
    const float* __restrict__ t_gt, float* __restrict__ out) {
    float v = 0.0f;
    for (int i = threadIdx.x; i < 2 * BATCH * NPTS; i += 1024)
        v += __uint_as_float(mins[i]);
    v *= 1.0f / (BATCH * NPTS);

    if (threadIdx.x == 0) {
        float acc = 0.0f;
        for (int b = 0; b < BATCH; ++b)
            for (int i = 0; i < 3; ++i)
                for (int k = 0; k < 3; ++k) {
                    float s = 0.0f;
                    for (int j = 0; j < 3; ++j)
                        s += R_gt[b * 9 + j * 3 + i] * R[b * 9 + j * 3 + k];
                    s -= (i == k) ? 1.0f : 0.0f;
                    acc += s * s;
                }
        for (int d = 0; d < 3; ++d)  // jnp.diagonal(S, axis1=0, axis2=1)
            for (int a = 0; a < 3; ++a) {
                const float diff = S[d * 9 + d * 3 + a] - S_gt[d * 9 + d * 3 + a];
                acc += diff * diff;
            }
        for (int b = 0; b < BATCH; ++b)
            for (int k = 0; k < 3; ++k) {
                const float diff = t[b * 3 + k] - t_gt[b * 3 + k];
                acc += diff * diff;
            }
        v += acc;
    }

    // block reduction: 16 waves of 64
    for (int off = 32; off; off >>= 1) v += __shfl_down(v, off, 64);
    __shared__ float wsum[16];
    const int lane = threadIdx.x & 63;
    const int wave = threadIdx.x >> 6;
    if (lane == 0) wsum[wave] = v;
    __syncthreads();
    if (wave == 0) {
        v = (lane < 16) ? wsum[lane] : 0.0f;
        for (int off = 8; off; off >>= 1) v += __shfl_down(v, off, 64);
        if (lane == 0) out[0] = v;
    }
}

extern "C" void kernel_launch(void* const* d_in, const int* in_sizes, int n_in,
                              void* d_out, int out_size, void* d_ws, size_t ws_size,
                              hipStream_t stream) {
    const float* x    = (const float*)d_in[0];
    const float* y    = (const float*)d_in[1];
    const float* R    = (const float*)d_in[2];
    const float* S    = (const float*)d_in[3];
    const float* t    = (const float*)d_in[4];
    const float* R_gt = (const float*)d_in[5];
    const float* S_gt = (const float*)d_in[6];
    const float* t_gt = (const float*)d_in[7];
    float* out = (float*)d_out;
    unsigned* mins = (unsigned*)d_ws;  // 2*B*N uints = 256 KiB

    // init mins to 0xFFFFFFFF (uint max) for atomicMin
    hipMemsetAsync(mins, 0xFF, (size_t)2 * BATCH * NPTS * sizeof(unsigned), stream);

    chamfer_kernel<<<dim3(QBLOCKS * SEGS, BATCH, 2), dim3(BLOCK), 0, stream>>>(x, y, mins);

    finalize_kernel<<<dim3(1), dim3(1024), 0, stream>>>(mins, R, S, t, R_gt, S_gt, t_gt, out);
}

// Round 7
// 112.250 us; speedup vs baseline: 3.1825x; 1.1164x over previous
//
#include <hip/hip_runtime.h>

#define NPTS 8192
#define BATCH 4
#define BLOCK 256
#define NQ 4                   // queries per thread (register-blocked) — R3-proven
#define QPB (BLOCK * NQ)       // 1024 queries per block
#define QBLOCKS (NPTS / QPB)   // 8
#define SEGS 32
#define SEGLEN (NPTS / SEGS)   // 256 targets per segment

// ---------------------------------------------------------------------------
// chamfer: grid (QBLOCKS*SEGS, BATCH, 2). Expanded form d = |p|^2+|q|^2-2p.q.
// LDS: tgtA[j]={x0,x1,y0,y1}, tgtB[j]={z0,z1,|q0|^2,|q1|^2} (paired targets).
// Per 2 targets per wave: 2 ds_read_b128 + NQ*(6 fma + 1 min3).
// Partial mins merged via atomicMin on float bits (distances clamped >= 0,
// so uint order == float order); mins initialized to 0xFFFFFFFF by memset.
// This kernel is identical to the Round-3 run that passed at 45 us.
// ---------------------------------------------------------------------------
__global__ __launch_bounds__(256) void chamfer_kernel(
    const float* __restrict__ x, const float* __restrict__ y,
    unsigned* __restrict__ mins) {
    __shared__ float4 tgtA[SEGLEN / 2];
    __shared__ float4 tgtB[SEGLEN / 2];

    const int dir = blockIdx.z;
    const int b = blockIdx.y;
    const int seg = blockIdx.x & (SEGS - 1);
    const int qb = blockIdx.x >> 5;  // / SEGS

    const float* pts = dir ? y : x;  // query set
    const float* oth = dir ? x : y;  // target set

    // stage one segment: one point per thread (SEGLEN == BLOCK)
    {
        const int p = threadIdx.x;
        const float* q = oth + ((size_t)b * NPTS + seg * SEGLEN + p) * 3;
        const float qx = q[0], qy = q[1], qz = q[2];
        const float sq = fmaf(qz, qz, fmaf(qy, qy, qx * qx));
        float* A = (float*)tgtA;
        float* Bv = (float*)tgtB;
        const int pi = p >> 1, par = p & 1;
        A[pi * 4 + par] = qx;
        A[pi * 4 + 2 + par] = qy;
        Bv[pi * 4 + par] = qz;
        Bv[pi * 4 + 2 + par] = sq;
    }

    // query points -> registers (-2*p components; |p|^2 folded in at the end)
    float m2x[NQ], m2y[NQ], m2z[NQ], sp[NQ], best[NQ];
    const int qbase = b * NPTS + qb * QPB + (int)threadIdx.x;
#pragma unroll
    for (int k = 0; k < NQ; ++k) {
        const float* p = pts + (size_t)(qbase + k * BLOCK) * 3;
        const float px = p[0], py = p[1], pz = p[2];
        m2x[k] = -2.0f * px;
        m2y[k] = -2.0f * py;
        m2z[k] = -2.0f * pz;
        sp[k] = fmaf(pz, pz, fmaf(py, py, px * px));
        best[k] = 3.0e38f;
    }

    __syncthreads();

#pragma unroll 2
    for (int j = 0; j < SEGLEN / 2; ++j) {
        const float4 A = tgtA[j];
        const float4 Bv = tgtB[j];
#pragma unroll
        for (int k = 0; k < NQ; ++k) {
            float d0 = fmaf(m2x[k], A.x, Bv.z);   // x0, sq0
            d0 = fmaf(m2y[k], A.z, d0);           // y0
            d0 = fmaf(m2z[k], Bv.x, d0);          // z0
            float d1 = fmaf(m2x[k], A.y, Bv.w);   // x1, sq1
            d1 = fmaf(m2y[k], A.w, d1);           // y1
            d1 = fmaf(m2z[k], Bv.y, d1);          // z1
            best[k] = fminf(fminf(best[k], d0), d1);  // v_min3_f32
        }
    }

    unsigned* om = mins + (size_t)(dir * BATCH + b) * NPTS + qb * QPB + threadIdx.x;
#pragma unroll
    for (int k = 0; k < NQ; ++k) {
        const float d = fmaxf(sp[k] + best[k], 0.0f);  // >=0: uint order == float order
        atomicMin(&om[k * BLOCK], __float_as_uint(d));
    }
}

// ---------------------------------------------------------------------------
// finalize: 64 blocks x 256 threads. Each block sums a 4 KB slice of the
// mins array (uint4 loads, fully coalesced, whole-GPU parallel), reduces,
// and atomicAdds its partial * 1/(B*N) into out[0] (pre-zeroed by memset).
// Block 0 / thread 0 adds the tiny regularizer term.
// ---------------------------------------------------------------------------
__global__ __launch_bounds__(256) void finalize_kernel(
    const unsigned* __restrict__ mins, const float* __restrict__ R,
    const float* __restrict__ S, const float* __restrict__ t,
    const float* __restrict__ R_gt, const float* __restrict__ S_gt,
    const float* __restrict__ t_gt, float* __restrict__ out) {
    const uint4* m4 = (const uint4*)mins;  // 2*B*N/4 = 16384 uint4s
    const int gid = blockIdx.x * 256 + (int)threadIdx.x;  // 0..16383
    const uint4 u = m4[gid];
    float v = (__uint_as_float(u.x) + __uint_as_float(u.y) +
               __uint_as_float(u.z) + __uint_as_float(u.w)) *
              (1.0f / (BATCH * NPTS));

    if (gid == 0) {
        float acc = 0.0f;
        for (int b = 0; b < BATCH; ++b)
            for (int i = 0; i < 3; ++i)
                for (int k = 0; k < 3; ++k) {
                    float s = 0.0f;
                    for (int j = 0; j < 3; ++j)
                        s += R_gt[b * 9 + j * 3 + i] * R[b * 9 + j * 3 + k];
                    s -= (i == k) ? 1.0f : 0.0f;
                    acc += s * s;
                }
        for (int d = 0; d < 3; ++d)  // jnp.diagonal(S, axis1=0, axis2=1)
            for (int a = 0; a < 3; ++a) {
                const float diff = S[d * 9 + d * 3 + a] - S_gt[d * 9 + d * 3 + a];
                acc += diff * diff;
            }
        for (int b = 0; b < BATCH; ++b)
            for (int k = 0; k < 3; ++k) {
                const float diff = t[b * 3 + k] - t_gt[b * 3 + k];
                acc += diff * diff;
            }
        v += acc;
    }

    // block reduction: 4 waves of 64
    for (int off = 32; off; off >>= 1) v += __shfl_down(v, off, 64);
    __shared__ float wsum[4];
    const int lane = threadIdx.x & 63;
    const int wave = threadIdx.x >> 6;
    if (lane == 0) wsum[wave] = v;
    __syncthreads();
    if (wave == 0) {
        v = (lane < 4) ? wsum[lane] : 0.0f;
        for (int off = 2; off; off >>= 1) v += __shfl_down(v, off, 64);
        if (lane == 0) atomicAdd(out, v);
    }
}

extern "C" void kernel_launch(void* const* d_in, const int* in_sizes, int n_in,
                              void* d_out, int out_size, void* d_ws, size_t ws_size,
                              hipStream_t stream) {
    const float* x    = (const float*)d_in[0];
    const float* y    = (const float*)d_in[1];
    const float* R    = (const float*)d_in[2];
    const float* S    = (const float*)d_in[3];
    const float* t    = (const float*)d_in[4];
    const float* R_gt = (const float*)d_in[5];
    const float* S_gt = (const float*)d_in[6];
    const float* t_gt = (const float*)d_in[7];
    float* out = (float*)d_out;
    unsigned* mins = (unsigned*)d_ws;  // 2*B*N uints = 256 KiB

    // init mins to 0xFFFFFFFF (uint max) for atomicMin; zero the scalar out.
    hipMemsetAsync(mins, 0xFF, (size_t)2 * BATCH * NPTS * sizeof(unsigned), stream);
    hipMemsetAsync(out, 0, sizeof(float), stream);

    chamfer_kernel<<<dim3(QBLOCKS * SEGS, BATCH, 2), dim3(BLOCK), 0, stream>>>(x, y, mins);

    finalize_kernel<<<dim3(2 * BATCH * NPTS / 4 / 256), dim3(BLOCK), 0, stream>>>(
        mins, R, S, t, R_gt, S_gt, t_gt, out);
}